// Round 17
// baseline (257.142 us; speedup 1.0000x reference)
//
#include <hip/hip_runtime.h>
#include <hip/hip_bf16.h>

#define HC1 512   // layer-1 heads*channels (4*128)
#define HC2 256   // layer-2 (1*256)
#define D_IN 256
#define CAP  128  // per-node edge bin capacity (max degree ~58 incl. margin)

typedef __hip_bfloat16  bf16;
typedef __hip_bfloat162 bf162;
typedef __attribute__((ext_vector_type(8))) short short8;   // 8 bf16 = 4 VGPR
typedef __attribute__((ext_vector_type(4))) float f32x4;
typedef __attribute__((ext_vector_type(2))) float f32x2;    // -> v_pk_*_f32

// unpack 4 u32 (8 bf16) into 4 channel-pairs (lo = even ch, hi = odd ch)
__device__ __forceinline__ void unpack8p(short8 q, f32x2* xa) {
  union { short8 s; unsigned u[4]; } uu; uu.s = q;
#pragma unroll
  for (int j = 0; j < 4; j++) {
    union { unsigned u; float f; } lo, hi;
    lo.u = uu.u[j] << 16;
    hi.u = uu.u[j] & 0xffff0000u;
    xa[j].x = lo.f; xa[j].y = hi.f;
  }
}
// load 8 consecutive f32 as 4 pairs
__device__ __forceinline__ void load8p(const float* p, f32x2* d) {
  float4 a = *(const float4*)p, b = *(const float4*)(p + 4);
  d[0].x = a.x; d[0].y = a.y; d[1].x = a.z; d[1].y = a.w;
  d[2].x = b.x; d[2].y = b.y; d[3].x = b.z; d[3].y = b.w;
}

// DPP-based partial-wave add on the VALU pipe (no LDS).
template <int CTRL>
__device__ __forceinline__ float dppadd(float x) {
  union { float f; int i; } u, v;
  u.f = x;
  v.i = __builtin_amdgcn_update_dpp(0, u.i, CTRL, 0xF, 0xF, true);
  return x + v.f;
}
// sum over each 16-lane group (result in every lane of the group)
__device__ __forceinline__ float red16(float p) {
  p = dppadd<0xB1>(p);    // quad_perm xor1
  p = dppadd<0x4E>(p);    // quad_perm xor2
  p = dppadd<0x124>(p);   // row_ror:4
  p = dppadd<0x128>(p);   // row_ror:8
  return p;
}

// ------------------------- async global->LDS (16B/lane) --------------------
__device__ __forceinline__ void glds16(const bf16* g, bf16* l) {
#if __has_builtin(__builtin_amdgcn_global_load_lds)
  __builtin_amdgcn_global_load_lds(
      (const __attribute__((address_space(1))) void*)g,
      (__attribute__((address_space(3))) void*)l, 16, 0, 0);
#else
  int lane = threadIdx.x & 63;
  ((int4*)l)[lane] = *(const int4*)g;
#endif
}

// ------------------------- bf16 MFMA GEMM ----------------------------------
// C[M,N] = A[M,K] @ BT[N,K]^T. Tile 128x128, BK=32, 4 waves, 64x64 each.
__global__ __launch_bounds__(256)
void gemm_mfma_kernel(const bf16* __restrict__ A, const bf16* __restrict__ BT,
                      bf16* __restrict__ C, int M, int K, int N) {
  __shared__ bf16 lds[8192];           // 16 KiB: A [0,4096), B [4096,8192)
  const int t = threadIdx.x;
  const int w  = t >> 6, l = t & 63;
  const int wr = w >> 1, wc = w & 1;
  const int lo = l & 15, hi = l >> 4;
  const int m0 = blockIdx.y * 128;
  const int n0 = blockIdx.x * 128;

  f32x4 acc[4][4] = {};

  const int c0 = w * 2, c1 = w * 2 + 1;
  const int kc0 = c0 >> 1, r0 = (c0 & 1) * 64 + l;
  const int kc1 = c1 >> 1, r1 = (c1 & 1) * 64 + l;
  int mr0 = m0 + r0; if (mr0 >= M) mr0 = M - 1;
  int mr1 = m0 + r1; if (mr1 >= M) mr1 = M - 1;
  const bf16* ga0 = A + (size_t)mr0 * K + kc0 * 8;
  const bf16* ga1 = A + (size_t)mr1 * K + kc1 * 8;
  const bf16* gb0 = BT + (size_t)(n0 + r0) * K + kc0 * 8;
  const bf16* gb1 = BT + (size_t)(n0 + r1) * K + kc1 * 8;
  bf16* la0 = &lds[c0 * 512];
  bf16* la1 = &lds[c1 * 512];
  bf16* lb0 = &lds[4096 + c0 * 512];
  bf16* lb1 = &lds[4096 + c1 * 512];

  for (int k0 = 0; k0 < K; k0 += 32) {
    if (k0) __syncthreads();
    glds16(ga0 + k0, la0);
    glds16(ga1 + k0, la1);
    glds16(gb0 + k0, lb0);
    glds16(gb1 + k0, lb1);
    __syncthreads();

    short8 af[4], bfr[4];
#pragma unroll
    for (int f = 0; f < 4; f++) {
      af[f]  = *(const short8*)&lds[hi * 1024 + (wr * 64 + f * 16 + lo) * 8];
      bfr[f] = *(const short8*)&lds[4096 + hi * 1024 + (wc * 64 + f * 16 + lo) * 8];
    }
#pragma unroll
    for (int fm = 0; fm < 4; fm++)
#pragma unroll
      for (int fn = 0; fn < 4; fn++)
        acc[fm][fn] = __builtin_amdgcn_mfma_f32_16x16x32_bf16(af[fm], bfr[fn],
                                                              acc[fm][fn], 0, 0, 0);
  }

#pragma unroll
  for (int fm = 0; fm < 4; fm++) {
#pragma unroll
    for (int r = 0; r < 4; r++) {
      int row = m0 + wr * 64 + fm * 16 + hi * 4 + r;
      if (row < M) {
#pragma unroll
        for (int fn = 0; fn < 4; fn++) {
          int col = n0 + wc * 64 + fn * 16 + lo;
          C[(size_t)row * N + col] = __float2bfloat16(acc[fm][fn][r]);
        }
      }
    }
  }
}

// ------------------------- prep: x -> bf16 ---------------------------------
__global__ void convx_kernel(const float* __restrict__ x, bf16* __restrict__ xb, int n4) {
  int i = blockIdx.x * blockDim.x + threadIdx.x;
  if (i >= n4) return;
  float4 v = ((const float4*)x)[i];
  union { bf16 h[4]; uint2 u; } cv;
  cv.h[0] = __float2bfloat16(v.x); cv.h[1] = __float2bfloat16(v.y);
  cv.h[2] = __float2bfloat16(v.z); cv.h[3] = __float2bfloat16(v.w);
  ((uint2*)xb)[i] = cv.u;
}

// tiled LDS transpose: out[n][k] = bf16(in[k][n]); 4 jobs via blockIdx.z
__global__ __launch_bounds__(256)
void transw_kernel(const float* __restrict__ Wl1, const float* __restrict__ Wr1,
                   const float* __restrict__ Wl2, const float* __restrict__ Wr2,
                   bf16* __restrict__ W1T, bf16* __restrict__ W2T) {
  __shared__ float tile[32][33];
  const int z = blockIdx.z;
  const float* in; bf16* out; int K, Nn;
  if (z == 0)      { in = Wl1; out = W1T;             K = 256; Nn = 512; }
  else if (z == 1) { in = Wr1; out = W1T + 512 * 256; K = 256; Nn = 512; }
  else if (z == 2) { in = Wl2; out = W2T;             K = 512; Nn = 256; }
  else             { in = Wr2; out = W2T + 256 * 512; K = 512; Nn = 256; }
  const int nt = blockIdx.x * 32, kt = blockIdx.y * 32;
  if (nt >= Nn || kt >= K) return;
  const int tx = threadIdx.x & 31, ty = threadIdx.x >> 5;
#pragma unroll
  for (int j = 0; j < 4; j++)
    tile[ty + j * 8][tx] = in[(size_t)(kt + ty + j * 8) * Nn + nt + tx];
  __syncthreads();
#pragma unroll
  for (int j = 0; j < 4; j++)
    out[(size_t)(nt + ty + j * 8) * K + kt + tx] = __float2bfloat16(tile[tx][ty + j * 8]);
}

// -------- direct binning fill + edge-attr mean (block-reduced atomics) -----
__global__ __launch_bounds__(256)
void fill_kernel(const int* __restrict__ ei, const float* __restrict__ eattr,
                 int* __restrict__ cnt, int* __restrict__ srcs,
                 float4* __restrict__ eaC, float* __restrict__ sums, int E) {
  __shared__ float4 bred[4];
  int tid = blockIdx.x * blockDim.x + threadIdx.x;
  int stride = gridDim.x * blockDim.x;
  float l0 = 0.f, l1 = 0.f, l2 = 0.f, l3 = 0.f;
  for (int e = tid; e < E; e += stride) {
    int src = ei[e], dst = ei[E + e];
    float4 ea = ((const float4*)eattr)[e];
    int pos = atomicAdd(&cnt[dst], 1);
    if (pos < CAP) {
      int slot = dst * CAP + pos;
      srcs[slot] = src;
      eaC[slot] = ea;
    }
    l0 += ea.x; l1 += ea.y; l2 += ea.z; l3 += ea.w;
  }
#pragma unroll
  for (int o = 1; o < 64; o <<= 1) {
    l0 += __shfl_xor(l0, o); l1 += __shfl_xor(l1, o);
    l2 += __shfl_xor(l2, o); l3 += __shfl_xor(l3, o);
  }
  int wave = threadIdx.x >> 6, lane = threadIdx.x & 63;
  if (lane == 0) bred[wave] = make_float4(l0, l1, l2, l3);
  __syncthreads();
  if (threadIdx.x == 0) {
    float4 a = bred[0], b = bred[1], c = bred[2], d = bred[3];
    atomicAdd(&sums[0], a.x + b.x + c.x + d.x);
    atomicAdd(&sums[1], a.y + b.y + c.y + d.y);
    atomicAdd(&sums[2], a.z + b.z + c.z + d.z);
    atomicAdd(&sums[3], a.w + b.w + c.w + d.w);
  }
}

__global__ void meanw_kernel(const float* __restrict__ sums, float* __restrict__ mean4, float invE) {
  int t = threadIdx.x;
  if (t < 4) mean4[t] = sums[t] * invE;
}

// ---- layer 1 fused: block/node, LDS-staged gather pipeline (counted vmcnt)-
// xlr: [N][1024] bf16 = [xl(512) | xr(512)]; lane covers 8 ch, head = lane>>4.
// self-loop (src=v, ea=mean4) computed by wave 0 in-register.
__global__ __launch_bounds__(256, 4)
void fused1_kernel(const int* __restrict__ srcs, const float4* __restrict__ eaC,
                   const int* __restrict__ cnt, const float* __restrict__ mean4,
                   const bf16* __restrict__ xlr,
                   const float* __restrict__ We, const float* __restrict__ att,
                   const float* __restrict__ bias, const float* __restrict__ g,
                   const float* __restrict__ be, bf16* __restrict__ h1) {
  const int v = blockIdx.x;
  const int tid = threadIdx.x;
  const int wave = tid >> 6, lane = tid & 63;
  const int ch = lane * 8;

  __shared__ bf16 stage[4][2][4][512];   // 32 KiB: per-wave double-buffer, 4 edges
  bf16* stw = &stage[wave][0][0][0];

  f32x2 w0p[4], w1p[4], w2p[4], w3p[4], awp[4], xrp[4];
  load8p(We + 0 * HC1 + ch, w0p);
  load8p(We + 1 * HC1 + ch, w1p);
  load8p(We + 2 * HC1 + ch, w2p);
  load8p(We + 3 * HC1 + ch, w3p);
  load8p(att + ch, awp);
  unpack8p(*(const short8*)(xlr + (size_t)v * 1024 + 512 + ch), xrp);

  int len = cnt[v]; if (len > CAP) len = CAP;
  const int beg = v * CAP, end = beg + len;
  const int chunk = (len + 3) >> 2;       // contiguous quarter per wave
  int ib = beg + wave * chunk;
  int ie = ib + chunk;
  if (ib > end) ib = end;
  if (ie > end) ie = end;

  float den = 0.f;
  f32x2 accp[4] = {};

  auto edge = [&](short8 q, float4 e) {
    f32x2 xa[4]; unpack8p(q, xa);
    f32x2 p2 = {0.f, 0.f};
#pragma unroll
    for (int j = 0; j < 4; j++) {
      f32x2 m = xa[j] + xrp[j];
      m += e.x * w0p[j];
      m += e.y * w1p[j];
      m += e.z * w2p[j];
      m += e.w * w3p[j];
      f32x2 lm = __builtin_elementwise_max(m, m * 0.2f);   // leaky (slope<1)
      p2 += lm * awp[j];
    }
    float p = p2.x + p2.y;
    p = red16(p);                       // per-head sum via DPP (VALU pipe)
    float ex = __expf(p);
    den += ex;
#pragma unroll
    for (int j = 0; j < 4; j++) accp[j] += xa[j] * ex;
  };

  int i = ib;
  if (i + 4 <= ie) {
    // prologue: issue batch 0 into buf 0
    int s0 = srcs[i], s1 = srcs[i + 1], s2 = srcs[i + 2], s3 = srcs[i + 3];
    float4 ec0 = eaC[i], ec1 = eaC[i + 1], ec2 = eaC[i + 2], ec3 = eaC[i + 3];
    __builtin_amdgcn_sched_barrier(0);
    glds16(xlr + (size_t)s0 * 1024 + ch, stw);
    glds16(xlr + (size_t)s1 * 1024 + ch, stw + 512);
    glds16(xlr + (size_t)s2 * 1024 + ch, stw + 1024);
    glds16(xlr + (size_t)s3 * 1024 + ch, stw + 1536);
    i += 4;
    int cur = 0;
    for (;;) {
      bf16* stc = cur ? (stw + 2048) : stw;
      const bool more = (i + 4 <= ie);
      float4 en0, en1, en2, en3;
      if (more) {
        int t0 = srcs[i], t1 = srcs[i + 1], t2 = srcs[i + 2], t3 = srcs[i + 3];
        en0 = eaC[i]; en1 = eaC[i + 1]; en2 = eaC[i + 2]; en3 = eaC[i + 3];
        __builtin_amdgcn_sched_barrier(0);   // pin srcs/eaC loads before glds
        bf16* stn = cur ? stw : (stw + 2048);
        glds16(xlr + (size_t)t0 * 1024 + ch, stn);
        glds16(xlr + (size_t)t1 * 1024 + ch, stn + 512);
        glds16(xlr + (size_t)t2 * 1024 + ch, stn + 1024);
        glds16(xlr + (size_t)t3 * 1024 + ch, stn + 1536);
        asm volatile("s_waitcnt vmcnt(4)" ::: "memory");   // batch cur ready
      } else {
        asm volatile("s_waitcnt vmcnt(0)" ::: "memory");
      }
      __builtin_amdgcn_sched_barrier(0);
      short8 q0 = *(const short8*)(stc + lane * 8);
      short8 q1 = *(const short8*)(stc + 512 + lane * 8);
      short8 q2 = *(const short8*)(stc + 1024 + lane * 8);
      short8 q3 = *(const short8*)(stc + 1536 + lane * 8);
      edge(q0, ec0); edge(q1, ec1); edge(q2, ec2); edge(q3, ec3);
      if (!more) break;
      ec0 = en0; ec1 = en1; ec2 = en2; ec3 = en3;
      cur ^= 1;
      i += 4;
    }
  }
  for (; i < ie; ++i) {                   // tail: direct global loads
    int s0 = srcs[i];
    float4 e0 = eaC[i];
    short8 q0 = *(const short8*)(xlr + (size_t)s0 * 1024 + ch);
    edge(q0, e0);
  }
  if (wave == 0) {                        // self-loop edge
    float4 e0 = *(const float4*)mean4;
    short8 q0 = *(const short8*)(xlr + (size_t)v * 1024 + ch);
    edge(q0, e0);
  }

  // ----- cross-wave combine -----
  __shared__ float accs[4][HC1];
  __shared__ float dens[4][4];     // [wave][head]
  __shared__ float2 red[4];
  *(float4*)&accs[wave][ch]     = *(float4*)&accp[0];
  *(float4*)&accs[wave][ch + 4] = *(float4*)&accp[2];
  if ((lane & 15) == 0) dens[wave][lane >> 4] = den;   // per-head partial
  __syncthreads();

  const int c = tid * 2;          // each thread: 2 channels for epilogue
  const int head = c >> 7;        // 128 channels per head
  const float dtot = dens[0][head] + dens[1][head] + dens[2][head] + dens[3][head];
  const float rden = 1.f / (dtot + 1e-16f);
  float2 a0 = *(float2*)&accs[0][c];
  float2 a1 = *(float2*)&accs[1][c];
  float2 a2 = *(float2*)&accs[2][c];
  float2 a3 = *(float2*)&accs[3][c];
  float2 bv = *(const float2*)(bias + c);
  float val0 = (a0.x + a1.x + a2.x + a3.x) * rden + bv.x;
  float val1 = (a0.y + a1.y + a2.y + a3.y) * rden + bv.y;

  float s1 = val0 + val1, s2 = val0 * val0 + val1 * val1;
  s1 = red16(s1); s2 = red16(s2);
  s1 += __shfl_xor(s1, 16); s2 += __shfl_xor(s2, 16);
  s1 += __shfl_xor(s1, 32); s2 += __shfl_xor(s2, 32);
  if (lane == 0) red[wave] = make_float2(s1, s2);
  __syncthreads();
  float ts1 = red[0].x + red[1].x + red[2].x + red[3].x;
  float ts2 = red[0].y + red[1].y + red[2].y + red[3].y;
  float mu  = ts1 * (1.f / HC1);
  float var = ts2 * (1.f / HC1) - mu * mu;
  float rs  = rsqrtf(var + 1e-5f);

  float2 gv = *(const float2*)(g + c);
  float2 ev = *(const float2*)(be + c);
  float ya = (val0 - mu) * rs * gv.x + ev.x;
  float yb = (val1 - mu) * rs * gv.y + ev.y;
  ya = (ya > 0.f) ? ya : expm1f(ya);
  yb = (yb > 0.f) ? yb : expm1f(yb);
  bf162 hv;
  hv.x = __float2bfloat16(ya); hv.y = __float2bfloat16(yb);
  *(bf162*)(h1 + (size_t)v * HC1 + c) = hv;
}

// ---- layer 2 fused: half-wave 2-edge layout, 16B/lane gathers -------------
// xlr: [N][512] bf16 = [xl(256) | xr(256)].
// lanes 0-31 = edge A, lanes 32-63 = edge B; each lane covers 8 ch (hl*8).
__global__ __launch_bounds__(256, 3)
void fused2_kernel(const int* __restrict__ srcs, const float4* __restrict__ eaC,
                   const int* __restrict__ cnt, const float* __restrict__ mean4,
                   const bf16* __restrict__ xlr,
                   const float* __restrict__ We, const float* __restrict__ att,
                   const float* __restrict__ bias, const float* __restrict__ g,
                   const float* __restrict__ be, const float* __restrict__ xin,
                   float* __restrict__ out) {
  const int v = blockIdx.x;
  const int tid = threadIdx.x;
  const int wave = tid >> 6, lane = tid & 63;
  const int half = lane >> 5;          // 0: edge A, 1: edge B
  const int hl = lane & 31;
  const int c0 = hl * 8;               // 8 channels per lane

  f32x2 w0p[4], w1p[4], w2p[4], w3p[4], atp[4], xrp[4];
  load8p(We + 0 * HC2 + c0, w0p);
  load8p(We + 1 * HC2 + c0, w1p);
  load8p(We + 2 * HC2 + c0, w2p);
  load8p(We + 3 * HC2 + c0, w3p);
  load8p(att + c0, atp);
  unpack8p(*(const short8*)(xlr + (size_t)v * 512 + 256 + c0), xrp);

  int len = cnt[v]; if (len > CAP) len = CAP;
  const int beg = v * CAP, end = beg + len;
  const int chunk = (len + 3) >> 2;
  int ib = beg + wave * chunk;
  int ie = ib + chunk;
  if (ib > end) ib = end;
  if (ie > end) ie = end;

  float den = 0.f;                 // per-half partial (A-half / B-half)
  f32x2 accp[4] = {};

  // one PAIR of edges (A in lanes<32, B in lanes>=32). bvalid: B edge exists.
  auto pair = [&](short8 q, float4 e, bool bvalid) {
    f32x2 xa[4]; unpack8p(q, xa);
    f32x2 p2 = {0.f, 0.f};
#pragma unroll
    for (int j = 0; j < 4; j++) {
      f32x2 m = xa[j] + xrp[j];
      m += e.x * w0p[j];
      m += e.y * w1p[j];
      m += e.z * w2p[j];
      m += e.w * w3p[j];
      f32x2 lm = __builtin_elementwise_max(m, m * 0.2f);
      p2 += lm * atp[j];
    }
    float p = p2.x + p2.y;
    p = red16(p);
    p += __shfl_xor(p, 16);          // sum over 32-lane half
    float ex = __expf(p);
    if (half && !bvalid) ex = 0.f;   // mask missing B edge
    den += ex;
#pragma unroll
    for (int j = 0; j < 4; j++) accp[j] += xa[j] * ex;
  };

  int i = ib;
  for (; i + 4 <= ie; i += 4) {
    int sA = srcs[i + half],   sB = srcs[i + 2 + half];
    float4 eA = eaC[i + half], eB = eaC[i + 2 + half];
    short8 qA = *(const short8*)(xlr + (size_t)sA * 512 + c0);
    short8 qB = *(const short8*)(xlr + (size_t)sB * 512 + c0);
    pair(qA, eA, true); pair(qB, eB, true);
  }
  for (; i < ie; i += 2) {
    bool hasB = (i + 1 < ie);
    int idx = i + half; if (idx > ie - 1) idx = i;   // clamp invalid B
    int s = srcs[idx];
    float4 e = eaC[idx];
    short8 q = *(const short8*)(xlr + (size_t)s * 512 + c0);
    pair(q, e, hasB);
  }
  if (wave == 0) {                   // self-loop edge (A half only)
    float4 e = *(const float4*)mean4;
    short8 q = *(const short8*)(xlr + (size_t)v * 512 + c0);
    pair(q, e, false);
  }

  // combine the two halves (each lane hl holds same channels in both halves)
#pragma unroll
  for (int j = 0; j < 4; j++) {
    accp[j].x += __shfl_xor(accp[j].x, 32);
    accp[j].y += __shfl_xor(accp[j].y, 32);
  }
  den += __shfl_xor(den, 32);

  // ----- cross-wave combine -----
  __shared__ float accs[4][HC2];
  __shared__ float dens[4];
  __shared__ float2 red[4];
  if (half == 0) {
    *(float4*)&accs[wave][c0]     = *(float4*)&accp[0];
    *(float4*)&accs[wave][c0 + 4] = *(float4*)&accp[2];
  }
  if (lane == 0) dens[wave] = den;
  __syncthreads();

  const int c = tid;              // each thread: 1 channel
  const float dtot = dens[0] + dens[1] + dens[2] + dens[3];
  const float rden = 1.f / (dtot + 1e-16f);
  float val = (accs[0][c] + accs[1][c] + accs[2][c] + accs[3][c]) * rden + bias[c];

  float s1 = val, s2 = val * val;
  s1 = red16(s1); s2 = red16(s2);
  s1 += __shfl_xor(s1, 16); s2 += __shfl_xor(s2, 16);
  s1 += __shfl_xor(s1, 32); s2 += __shfl_xor(s2, 32);
  if (lane == 0) red[wave] = make_float2(s1, s2);
  __syncthreads();
  float ts1 = red[0].x + red[1].x + red[2].x + red[3].x;
  float ts2 = red[0].y + red[1].y + red[2].y + red[3].y;
  float mu  = ts1 * (1.f / HC2);
  float var = ts2 * (1.f / HC2) - mu * mu;
  float rs  = rsqrtf(var + 1e-5f);
  float y = (val - mu) * rs * g[c] + be[c];
  out[(size_t)v * HC2 + c] = y + xin[(size_t)v * HC2 + c];
}

// ---------------------------------------------------------------------------
extern "C" void kernel_launch(void* const* d_in, const int* in_sizes, int n_in,
                              void* d_out, int out_size, void* d_ws, size_t ws_size,
                              hipStream_t stream) {
  const float* x     = (const float*)d_in[0];
  const int*   ei    = (const int*)d_in[1];
  const float* eattr = (const float*)d_in[2];
  const float* Wl1   = (const float*)d_in[3];
  const float* Wr1   = (const float*)d_in[4];
  const float* We1   = (const float*)d_in[5];
  const float* att1  = (const float*)d_in[6];
  const float* b1    = (const float*)d_in[7];
  const float* g1    = (const float*)d_in[8];
  const float* be1   = (const float*)d_in[9];
  const float* Wl2   = (const float*)d_in[10];
  const float* Wr2   = (const float*)d_in[11];
  const float* We2   = (const float*)d_in[12];
  const float* att2  = (const float*)d_in[13];
  const float* b2    = (const float*)d_in[14];
  const float* g2    = (const float*)d_in[15];
  const float* be2   = (const float*)d_in[16];

  const int N    = in_sizes[0] / D_IN;   // 10000
  const int E    = in_sizes[2] / 4;      // 320000

  char* w = (char*)d_ws;
  auto alloc = [&](size_t bytes) -> void* {
    void* p = (void*)w;
    w += (bytes + 255) & ~(size_t)255;
    return p;
  };
  bf16*   xb    = (bf16*)alloc((size_t)N * D_IN * 2);
  bf16*   W1T   = (bf16*)alloc((size_t)1024 * 256 * 2);
  bf16*   W2T   = (bf16*)alloc((size_t)512 * 512 * 2);
  bf16*   xlr1  = (bf16*)alloc((size_t)N * 1024 * 2);
  bf16*   h1    = (bf16*)alloc((size_t)N * HC1 * 2);
  bf16*   xlr2  = (bf16*)alloc((size_t)N * 512 * 2);
  int*    srcs  = (int*)alloc((size_t)N * CAP * 4);
  float4* eaC   = (float4*)alloc((size_t)N * CAP * 16);
  float*  mean4 = (float*)alloc(64);
  char*   zb    = w;                     // zeroed region
  int*    cnt   = (int*)alloc((size_t)N * 4);
  float*  sums  = (float*)alloc(64);
  size_t  zbytes = (size_t)(w - zb);

  hipMemsetAsync(zb, 0, zbytes, stream);

  int n4 = N * D_IN / 4;
  convx_kernel<<<(n4 + 255) / 256, 256, 0, stream>>>(x, xb, n4);
  transw_kernel<<<dim3(16, 16, 4), 256, 0, stream>>>(Wl1, Wr1, Wl2, Wr2, W1T, W2T);

  fill_kernel<<<1024, 256, 0, stream>>>(ei, eattr, cnt, srcs, eaC, sums, E);
  meanw_kernel<<<1, 64, 0, stream>>>(sums, mean4, 1.f / (float)E);

  dim3 gg1(1024 / 128, (N + 127) / 128);
  gemm_mfma_kernel<<<gg1, 256, 0, stream>>>(xb, W1T, xlr1, N, 256, 1024);

  fused1_kernel<<<N, 256, 0, stream>>>(srcs, eaC, cnt, mean4, xlr1, We1, att1,
                                       b1, g1, be1, h1);

  dim3 gg2(512 / 128, (N + 127) / 128);
  gemm_mfma_kernel<<<gg2, 256, 0, stream>>>(h1, W2T, xlr2, N, 512, 512);

  fused2_kernel<<<N, 256, 0, stream>>>(srcs, eaC, cnt, mean4, xlr2, We2, att2,
                                       b2, g2, be2, x, (float*)d_out);
}

// Round 18
// 248.692 us; speedup vs baseline: 1.0340x; 1.0340x over previous
//
#include <hip/hip_runtime.h>
#include <hip/hip_bf16.h>

#define HC1 512   // layer-1 heads*channels (4*128)
#define HC2 256   // layer-2 (1*256)
#define D_IN 256
#define CAP  128  // per-node edge bin capacity (max degree ~58 incl. margin)

typedef __hip_bfloat16  bf16;
typedef __hip_bfloat162 bf162;
typedef __attribute__((ext_vector_type(8))) short short8;   // 8 bf16 = 4 VGPR
typedef __attribute__((ext_vector_type(4))) float f32x4;
typedef __attribute__((ext_vector_type(2))) float f32x2;    // -> v_pk_*_f32

// unpack 4 u32 (8 bf16) into 4 channel-pairs (lo = even ch, hi = odd ch)
__device__ __forceinline__ void unpack8p(short8 q, f32x2* xa) {
  union { short8 s; unsigned u[4]; } uu; uu.s = q;
#pragma unroll
  for (int j = 0; j < 4; j++) {
    union { unsigned u; float f; } lo, hi;
    lo.u = uu.u[j] << 16;
    hi.u = uu.u[j] & 0xffff0000u;
    xa[j].x = lo.f; xa[j].y = hi.f;
  }
}
// load 8 consecutive f32 as 4 pairs
__device__ __forceinline__ void load8p(const float* p, f32x2* d) {
  float4 a = *(const float4*)p, b = *(const float4*)(p + 4);
  d[0].x = a.x; d[0].y = a.y; d[1].x = a.z; d[1].y = a.w;
  d[2].x = b.x; d[2].y = b.y; d[3].x = b.z; d[3].y = b.w;
}

// DPP-based partial-wave add on the VALU pipe (no LDS).
template <int CTRL>
__device__ __forceinline__ float dppadd(float x) {
  union { float f; int i; } u, v;
  u.f = x;
  v.i = __builtin_amdgcn_update_dpp(0, u.i, CTRL, 0xF, 0xF, true);
  return x + v.f;
}
// sum over each 16-lane group (result in every lane of the group)
__device__ __forceinline__ float red16(float p) {
  p = dppadd<0xB1>(p);    // quad_perm xor1
  p = dppadd<0x4E>(p);    // quad_perm xor2
  p = dppadd<0x124>(p);   // row_ror:4
  p = dppadd<0x128>(p);   // row_ror:8
  return p;
}

// ------------------------- async global->LDS (16B/lane) --------------------
__device__ __forceinline__ void glds16(const bf16* g, bf16* l) {
#if __has_builtin(__builtin_amdgcn_global_load_lds)
  __builtin_amdgcn_global_load_lds(
      (const __attribute__((address_space(1))) void*)g,
      (__attribute__((address_space(3))) void*)l, 16, 0, 0);
#else
  int lane = threadIdx.x & 63;
  ((int4*)l)[lane] = *(const int4*)g;
#endif
}

// ------------------------- bf16 MFMA GEMM ----------------------------------
// C[M,N] = A[M,K] @ BT[N,K]^T. Tile 64x128, BK=32, 4 waves, 32x64 each.
// Small M-tile -> 2x the workgroups (latency hiding via parallelism).
__global__ __launch_bounds__(256)
void gemm_mfma_kernel(const bf16* __restrict__ A, const bf16* __restrict__ BT,
                      bf16* __restrict__ C, int M, int K, int N) {
  __shared__ bf16 lds[6144];           // 12 KiB: A [0,2048), B [2048,6144)
  const int t = threadIdx.x;
  const int w  = t >> 6, l = t & 63;
  const int wr = w >> 1, wc = w & 1;
  const int lo = l & 15, hi = l >> 4;
  const int m0 = blockIdx.y * 64;
  const int n0 = blockIdx.x * 128;

  f32x4 acc[2][4] = {};

  // 3 staging chunks (1 KiB each) per wave: A has 4 chunks, B has 8.
  const bf16* gp[3];
  bf16* lp[3];
#pragma unroll
  for (int j = 0; j < 3; j++) {
    int c = w * 3 + j;
    if (c < 4) {                       // A chunk: rows 0..63, k-octet c
      int row = m0 + l; if (row >= M) row = M - 1;
      gp[j] = A + (size_t)row * K + c * 8;
      lp[j] = &lds[c * 512];
    } else {                           // B chunk
      int cb = c - 4;
      int col = (cb & 1) * 64 + l;
      gp[j] = BT + (size_t)(n0 + col) * K + (cb >> 1) * 8;
      lp[j] = &lds[2048 + cb * 512];
    }
  }

  for (int k0 = 0; k0 < K; k0 += 32) {
    if (k0) __syncthreads();
    glds16(gp[0] + k0, lp[0]);
    glds16(gp[1] + k0, lp[1]);
    glds16(gp[2] + k0, lp[2]);
    __syncthreads();

    short8 af[2], bfr[4];
#pragma unroll
    for (int fm = 0; fm < 2; fm++)
      af[fm] = *(const short8*)&lds[hi * 512 + (wr * 32 + fm * 16 + lo) * 8];
#pragma unroll
    for (int fn = 0; fn < 4; fn++)
      bfr[fn] = *(const short8*)&lds[2048 + hi * 1024 + (wc * 64 + fn * 16 + lo) * 8];
#pragma unroll
    for (int fm = 0; fm < 2; fm++)
#pragma unroll
      for (int fn = 0; fn < 4; fn++)
        acc[fm][fn] = __builtin_amdgcn_mfma_f32_16x16x32_bf16(af[fm], bfr[fn],
                                                              acc[fm][fn], 0, 0, 0);
  }

#pragma unroll
  for (int fm = 0; fm < 2; fm++) {
#pragma unroll
    for (int r = 0; r < 4; r++) {
      int row = m0 + wr * 32 + fm * 16 + hi * 4 + r;
      if (row < M) {
#pragma unroll
        for (int fn = 0; fn < 4; fn++) {
          int col = n0 + wc * 64 + fn * 16 + lo;
          C[(size_t)row * N + col] = __float2bfloat16(acc[fm][fn][r]);
        }
      }
    }
  }
}

// ------------------------- prep: x -> bf16 ---------------------------------
__global__ void convx_kernel(const float* __restrict__ x, bf16* __restrict__ xb, int n4) {
  int i = blockIdx.x * blockDim.x + threadIdx.x;
  if (i >= n4) return;
  float4 v = ((const float4*)x)[i];
  union { bf16 h[4]; uint2 u; } cv;
  cv.h[0] = __float2bfloat16(v.x); cv.h[1] = __float2bfloat16(v.y);
  cv.h[2] = __float2bfloat16(v.z); cv.h[3] = __float2bfloat16(v.w);
  ((uint2*)xb)[i] = cv.u;
}

// tiled LDS transpose: out[n][k] = bf16(in[k][n]); 4 jobs via blockIdx.z
__global__ __launch_bounds__(256)
void transw_kernel(const float* __restrict__ Wl1, const float* __restrict__ Wr1,
                   const float* __restrict__ Wl2, const float* __restrict__ Wr2,
                   bf16* __restrict__ W1T, bf16* __restrict__ W2T) {
  __shared__ float tile[32][33];
  const int z = blockIdx.z;
  const float* in; bf16* out; int K, Nn;
  if (z == 0)      { in = Wl1; out = W1T;             K = 256; Nn = 512; }
  else if (z == 1) { in = Wr1; out = W1T + 512 * 256; K = 256; Nn = 512; }
  else if (z == 2) { in = Wl2; out = W2T;             K = 512; Nn = 256; }
  else             { in = Wr2; out = W2T + 256 * 512; K = 512; Nn = 256; }
  const int nt = blockIdx.x * 32, kt = blockIdx.y * 32;
  if (nt >= Nn || kt >= K) return;
  const int tx = threadIdx.x & 31, ty = threadIdx.x >> 5;
#pragma unroll
  for (int j = 0; j < 4; j++)
    tile[ty + j * 8][tx] = in[(size_t)(kt + ty + j * 8) * Nn + nt + tx];
  __syncthreads();
#pragma unroll
  for (int j = 0; j < 4; j++)
    out[(size_t)(nt + ty + j * 8) * K + kt + tx] = __float2bfloat16(tile[tx][ty + j * 8]);
}

// -------- direct binning fill + edge-attr mean (block-reduced atomics) -----
__global__ __launch_bounds__(256)
void fill_kernel(const int* __restrict__ ei, const float* __restrict__ eattr,
                 int* __restrict__ cnt, int* __restrict__ srcs,
                 float4* __restrict__ eaC, float* __restrict__ sums, int E) {
  __shared__ float4 bred[4];
  int tid = blockIdx.x * blockDim.x + threadIdx.x;
  int stride = gridDim.x * blockDim.x;
  float l0 = 0.f, l1 = 0.f, l2 = 0.f, l3 = 0.f;
  for (int e = tid; e < E; e += stride) {
    int src = ei[e], dst = ei[E + e];
    float4 ea = ((const float4*)eattr)[e];
    int pos = atomicAdd(&cnt[dst], 1);
    if (pos < CAP) {
      int slot = dst * CAP + pos;
      srcs[slot] = src;
      eaC[slot] = ea;
    }
    l0 += ea.x; l1 += ea.y; l2 += ea.z; l3 += ea.w;
  }
#pragma unroll
  for (int o = 1; o < 64; o <<= 1) {
    l0 += __shfl_xor(l0, o); l1 += __shfl_xor(l1, o);
    l2 += __shfl_xor(l2, o); l3 += __shfl_xor(l3, o);
  }
  int wave = threadIdx.x >> 6, lane = threadIdx.x & 63;
  if (lane == 0) bred[wave] = make_float4(l0, l1, l2, l3);
  __syncthreads();
  if (threadIdx.x == 0) {
    float4 a = bred[0], b = bred[1], c = bred[2], d = bred[3];
    atomicAdd(&sums[0], a.x + b.x + c.x + d.x);
    atomicAdd(&sums[1], a.y + b.y + c.y + d.y);
    atomicAdd(&sums[2], a.z + b.z + c.z + d.z);
    atomicAdd(&sums[3], a.w + b.w + c.w + d.w);
  }
}

__global__ void meanw_kernel(const float* __restrict__ sums, float* __restrict__ mean4, float invE) {
  int t = threadIdx.x;
  if (t < 4) mean4[t] = sums[t] * invE;
}

// ---- layer 1 fused: block/node, chunked waves, 4x MLP, packed f32 ---------
// xlr: [N][1024] bf16 = [xl(512) | xr(512)]; lane covers 8 ch, head = lane>>4.
// self-loop (src=v, ea=mean4) computed by wave 0 in-register.
__global__ __launch_bounds__(256, 4)
void fused1_kernel(const int* __restrict__ srcs, const float4* __restrict__ eaC,
                   const int* __restrict__ cnt, const float* __restrict__ mean4,
                   const bf16* __restrict__ xlr,
                   const float* __restrict__ We, const float* __restrict__ att,
                   const float* __restrict__ bias, const float* __restrict__ g,
                   const float* __restrict__ be, bf16* __restrict__ h1) {
  const int v = blockIdx.x;
  const int tid = threadIdx.x;
  const int wave = tid >> 6, lane = tid & 63;
  const int ch = lane * 8;

  f32x2 w0p[4], w1p[4], w2p[4], w3p[4], awp[4], xrp[4];
  load8p(We + 0 * HC1 + ch, w0p);
  load8p(We + 1 * HC1 + ch, w1p);
  load8p(We + 2 * HC1 + ch, w2p);
  load8p(We + 3 * HC1 + ch, w3p);
  load8p(att + ch, awp);
  unpack8p(*(const short8*)(xlr + (size_t)v * 1024 + 512 + ch), xrp);

  int len = cnt[v]; if (len > CAP) len = CAP;
  const int beg = v * CAP, end = beg + len;
  const int chunk = (len + 3) >> 2;       // contiguous quarter per wave
  int ib = beg + wave * chunk;
  int ie = ib + chunk;
  if (ib > end) ib = end;
  if (ie > end) ie = end;

  float den = 0.f;
  f32x2 accp[4] = {};

  auto edge = [&](short8 q, float4 e) {
    f32x2 xa[4]; unpack8p(q, xa);
    f32x2 p2 = {0.f, 0.f};
#pragma unroll
    for (int j = 0; j < 4; j++) {
      f32x2 m = xa[j] + xrp[j];
      m += e.x * w0p[j];
      m += e.y * w1p[j];
      m += e.z * w2p[j];
      m += e.w * w3p[j];
      f32x2 lm = __builtin_elementwise_max(m, m * 0.2f);   // leaky (slope<1)
      p2 += lm * awp[j];
    }
    float p = p2.x + p2.y;
    p = red16(p);                       // per-head sum via DPP (VALU pipe)
    float ex = __expf(p);
    den += ex;
#pragma unroll
    for (int j = 0; j < 4; j++) accp[j] += xa[j] * ex;
  };

  int i = ib;
  for (; i + 4 <= ie; i += 4) {
    int s0 = srcs[i], s1 = srcs[i + 1], s2 = srcs[i + 2], s3 = srcs[i + 3];
    float4 e0 = eaC[i], e1 = eaC[i + 1], e2 = eaC[i + 2], e3 = eaC[i + 3];
    short8 q0 = *(const short8*)(xlr + (size_t)s0 * 1024 + ch);
    short8 q1 = *(const short8*)(xlr + (size_t)s1 * 1024 + ch);
    short8 q2 = *(const short8*)(xlr + (size_t)s2 * 1024 + ch);
    short8 q3 = *(const short8*)(xlr + (size_t)s3 * 1024 + ch);
    edge(q0, e0); edge(q1, e1); edge(q2, e2); edge(q3, e3);
  }
  for (; i < ie; ++i) {
    int s0 = srcs[i];
    float4 e0 = eaC[i];
    short8 q0 = *(const short8*)(xlr + (size_t)s0 * 1024 + ch);
    edge(q0, e0);
  }
  if (wave == 0) {                      // self-loop edge
    float4 e0 = *(const float4*)mean4;
    short8 q0 = *(const short8*)(xlr + (size_t)v * 1024 + ch);
    edge(q0, e0);
  }

  // ----- cross-wave combine -----
  __shared__ float accs[4][HC1];
  __shared__ float dens[4][4];     // [wave][head]
  __shared__ float2 red[4];
  *(float4*)&accs[wave][ch]     = *(float4*)&accp[0];
  *(float4*)&accs[wave][ch + 4] = *(float4*)&accp[2];
  if ((lane & 15) == 0) dens[wave][lane >> 4] = den;   // per-head partial
  __syncthreads();

  const int c = tid * 2;          // each thread: 2 channels for epilogue
  const int head = c >> 7;        // 128 channels per head
  const float dtot = dens[0][head] + dens[1][head] + dens[2][head] + dens[3][head];
  const float rden = 1.f / (dtot + 1e-16f);
  float2 a0 = *(float2*)&accs[0][c];
  float2 a1 = *(float2*)&accs[1][c];
  float2 a2 = *(float2*)&accs[2][c];
  float2 a3 = *(float2*)&accs[3][c];
  float2 bv = *(const float2*)(bias + c);
  float val0 = (a0.x + a1.x + a2.x + a3.x) * rden + bv.x;
  float val1 = (a0.y + a1.y + a2.y + a3.y) * rden + bv.y;

  float s1 = val0 + val1, s2 = val0 * val0 + val1 * val1;
  s1 = red16(s1); s2 = red16(s2);
  s1 += __shfl_xor(s1, 16); s2 += __shfl_xor(s2, 16);
  s1 += __shfl_xor(s1, 32); s2 += __shfl_xor(s2, 32);
  if (lane == 0) red[wave] = make_float2(s1, s2);
  __syncthreads();
  float ts1 = red[0].x + red[1].x + red[2].x + red[3].x;
  float ts2 = red[0].y + red[1].y + red[2].y + red[3].y;
  float mu  = ts1 * (1.f / HC1);
  float var = ts2 * (1.f / HC1) - mu * mu;
  float rs  = rsqrtf(var + 1e-5f);

  float2 gv = *(const float2*)(g + c);
  float2 ev = *(const float2*)(be + c);
  float ya = (val0 - mu) * rs * gv.x + ev.x;
  float yb = (val1 - mu) * rs * gv.y + ev.y;
  ya = (ya > 0.f) ? ya : expm1f(ya);
  yb = (yb > 0.f) ? yb : expm1f(yb);
  bf162 hv;
  hv.x = __float2bfloat16(ya); hv.y = __float2bfloat16(yb);
  *(bf162*)(h1 + (size_t)v * HC1 + c) = hv;
}

// ---- layer 2 fused: half-wave 2-edge layout, 16B/lane gathers -------------
// xlr: [N][512] bf16 = [xl(256) | xr(256)].
// lanes 0-31 = edge A, lanes 32-63 = edge B; each lane covers 8 ch (hl*8).
__global__ __launch_bounds__(256, 3)
void fused2_kernel(const int* __restrict__ srcs, const float4* __restrict__ eaC,
                   const int* __restrict__ cnt, const float* __restrict__ mean4,
                   const bf16* __restrict__ xlr,
                   const float* __restrict__ We, const float* __restrict__ att,
                   const float* __restrict__ bias, const float* __restrict__ g,
                   const float* __restrict__ be, const float* __restrict__ xin,
                   float* __restrict__ out) {
  const int v = blockIdx.x;
  const int tid = threadIdx.x;
  const int wave = tid >> 6, lane = tid & 63;
  const int half = lane >> 5;          // 0: edge A, 1: edge B
  const int hl = lane & 31;
  const int c0 = hl * 8;               // 8 channels per lane

  f32x2 w0p[4], w1p[4], w2p[4], w3p[4], atp[4], xrp[4];
  load8p(We + 0 * HC2 + c0, w0p);
  load8p(We + 1 * HC2 + c0, w1p);
  load8p(We + 2 * HC2 + c0, w2p);
  load8p(We + 3 * HC2 + c0, w3p);
  load8p(att + c0, atp);
  unpack8p(*(const short8*)(xlr + (size_t)v * 512 + 256 + c0), xrp);

  int len = cnt[v]; if (len > CAP) len = CAP;
  const int beg = v * CAP, end = beg + len;
  const int chunk = (len + 3) >> 2;
  int ib = beg + wave * chunk;
  int ie = ib + chunk;
  if (ib > end) ib = end;
  if (ie > end) ie = end;

  float den = 0.f;                 // per-half partial (A-half / B-half)
  f32x2 accp[4] = {};

  // one PAIR of edges (A in lanes<32, B in lanes>=32). bvalid: B edge exists.
  auto pair = [&](short8 q, float4 e, bool bvalid) {
    f32x2 xa[4]; unpack8p(q, xa);
    f32x2 p2 = {0.f, 0.f};
#pragma unroll
    for (int j = 0; j < 4; j++) {
      f32x2 m = xa[j] + xrp[j];
      m += e.x * w0p[j];
      m += e.y * w1p[j];
      m += e.z * w2p[j];
      m += e.w * w3p[j];
      f32x2 lm = __builtin_elementwise_max(m, m * 0.2f);
      p2 += lm * atp[j];
    }
    float p = p2.x + p2.y;
    p = red16(p);
    p += __shfl_xor(p, 16);          // sum over 32-lane half
    float ex = __expf(p);
    if (half && !bvalid) ex = 0.f;   // mask missing B edge
    den += ex;
#pragma unroll
    for (int j = 0; j < 4; j++) accp[j] += xa[j] * ex;
  };

  int i = ib;
  for (; i + 4 <= ie; i += 4) {
    int sA = srcs[i + half],   sB = srcs[i + 2 + half];
    float4 eA = eaC[i + half], eB = eaC[i + 2 + half];
    short8 qA = *(const short8*)(xlr + (size_t)sA * 512 + c0);
    short8 qB = *(const short8*)(xlr + (size_t)sB * 512 + c0);
    pair(qA, eA, true); pair(qB, eB, true);
  }
  for (; i < ie; i += 2) {
    bool hasB = (i + 1 < ie);
    int idx = i + half; if (idx > ie - 1) idx = i;   // clamp invalid B
    int s = srcs[idx];
    float4 e = eaC[idx];
    short8 q = *(const short8*)(xlr + (size_t)s * 512 + c0);
    pair(q, e, hasB);
  }
  if (wave == 0) {                   // self-loop edge (A half only)
    float4 e = *(const float4*)mean4;
    short8 q = *(const short8*)(xlr + (size_t)v * 512 + c0);
    pair(q, e, false);
  }

  // combine the two halves (each lane hl holds same channels in both halves)
#pragma unroll
  for (int j = 0; j < 4; j++) {
    accp[j].x += __shfl_xor(accp[j].x, 32);
    accp[j].y += __shfl_xor(accp[j].y, 32);
  }
  den += __shfl_xor(den, 32);

  // ----- cross-wave combine -----
  __shared__ float accs[4][HC2];
  __shared__ float dens[4];
  __shared__ float2 red[4];
  if (half == 0) {
    *(float4*)&accs[wave][c0]     = *(float4*)&accp[0];
    *(float4*)&accs[wave][c0 + 4] = *(float4*)&accp[2];
  }
  if (lane == 0) dens[wave] = den;
  __syncthreads();

  const int c = tid;              // each thread: 1 channel
  const float dtot = dens[0] + dens[1] + dens[2] + dens[3];
  const float rden = 1.f / (dtot + 1e-16f);
  float val = (accs[0][c] + accs[1][c] + accs[2][c] + accs[3][c]) * rden + bias[c];

  float s1 = val, s2 = val * val;
  s1 = red16(s1); s2 = red16(s2);
  s1 += __shfl_xor(s1, 16); s2 += __shfl_xor(s2, 16);
  s1 += __shfl_xor(s1, 32); s2 += __shfl_xor(s2, 32);
  if (lane == 0) red[wave] = make_float2(s1, s2);
  __syncthreads();
  float ts1 = red[0].x + red[1].x + red[2].x + red[3].x;
  float ts2 = red[0].y + red[1].y + red[2].y + red[3].y;
  float mu  = ts1 * (1.f / HC2);
  float var = ts2 * (1.f / HC2) - mu * mu;
  float rs  = rsqrtf(var + 1e-5f);
  float y = (val - mu) * rs * g[c] + be[c];
  out[(size_t)v * HC2 + c] = y + xin[(size_t)v * HC2 + c];
}

// ---------------------------------------------------------------------------
extern "C" void kernel_launch(void* const* d_in, const int* in_sizes, int n_in,
                              void* d_out, int out_size, void* d_ws, size_t ws_size,
                              hipStream_t stream) {
  const float* x     = (const float*)d_in[0];
  const int*   ei    = (const int*)d_in[1];
  const float* eattr = (const float*)d_in[2];
  const float* Wl1   = (const float*)d_in[3];
  const float* Wr1   = (const float*)d_in[4];
  const float* We1   = (const float*)d_in[5];
  const float* att1  = (const float*)d_in[6];
  const float* b1    = (const float*)d_in[7];
  const float* g1    = (const float*)d_in[8];
  const float* be1   = (const float*)d_in[9];
  const float* Wl2   = (const float*)d_in[10];
  const float* Wr2   = (const float*)d_in[11];
  const float* We2   = (const float*)d_in[12];
  const float* att2  = (const float*)d_in[13];
  const float* b2    = (const float*)d_in[14];
  const float* g2    = (const float*)d_in[15];
  const float* be2   = (const float*)d_in[16];

  const int N    = in_sizes[0] / D_IN;   // 10000
  const int E    = in_sizes[2] / 4;      // 320000

  char* w = (char*)d_ws;
  auto alloc = [&](size_t bytes) -> void* {
    void* p = (void*)w;
    w += (bytes + 255) & ~(size_t)255;
    return p;
  };
  bf16*   xb    = (bf16*)alloc((size_t)N * D_IN * 2);
  bf16*   W1T   = (bf16*)alloc((size_t)1024 * 256 * 2);
  bf16*   W2T   = (bf16*)alloc((size_t)512 * 512 * 2);
  bf16*   xlr1  = (bf16*)alloc((size_t)N * 1024 * 2);
  bf16*   h1    = (bf16*)alloc((size_t)N * HC1 * 2);
  bf16*   xlr2  = (bf16*)alloc((size_t)N * 512 * 2);
  int*    srcs  = (int*)alloc((size_t)N * CAP * 4);
  float4* eaC   = (float4*)alloc((size_t)N * CAP * 16);
  float*  mean4 = (float*)alloc(64);
  char*   zb    = w;                     // zeroed region
  int*    cnt   = (int*)alloc((size_t)N * 4);
  float*  sums  = (float*)alloc(64);
  size_t  zbytes = (size_t)(w - zb);

  hipMemsetAsync(zb, 0, zbytes, stream);

  int n4 = N * D_IN / 4;
  convx_kernel<<<(n4 + 255) / 256, 256, 0, stream>>>(x, xb, n4);
  transw_kernel<<<dim3(16, 16, 4), 256, 0, stream>>>(Wl1, Wr1, Wl2, Wr2, W1T, W2T);

  fill_kernel<<<1024, 256, 0, stream>>>(ei, eattr, cnt, srcs, eaC, sums, E);
  meanw_kernel<<<1, 64, 0, stream>>>(sums, mean4, 1.f / (float)E);

  dim3 gg1(1024 / 128, (N + 63) / 64);
  gemm_mfma_kernel<<<gg1, 256, 0, stream>>>(xb, W1T, xlr1, N, 256, 1024);

  fused1_kernel<<<N, 256, 0, stream>>>(srcs, eaC, cnt, mean4, xlr1, We1, att1,
                                       b1, g1, be1, h1);

  dim3 gg2(512 / 128, (N + 63) / 64);
  gemm_mfma_kernel<<<gg2, 256, 0, stream>>>(h1, W2T, xlr2, N, 512, 512);

  fused2_kernel<<<N, 256, 0, stream>>>(srcs, eaC, cnt, mean4, xlr2, We2, att2,
                                       b2, g2, be2, x, (float*)d_out);
}

// Round 19
// 242.569 us; speedup vs baseline: 1.0601x; 1.0252x over previous
//
#include <hip/hip_runtime.h>
#include <hip/hip_bf16.h>

#define HC1 512   // layer-1 heads*channels (4*128)
#define HC2 256   // layer-2 (1*256)
#define D_IN 256
#define CAP  128  // per-node edge bin capacity (max degree ~58 incl. margin)

typedef __hip_bfloat16  bf16;
typedef __hip_bfloat162 bf162;
typedef __attribute__((ext_vector_type(8))) short short8;   // 8 bf16 = 4 VGPR
typedef __attribute__((ext_vector_type(4))) float f32x4;
typedef __attribute__((ext_vector_type(2))) float f32x2;    // -> v_pk_*_f32

// unpack 4 u32 (8 bf16) into 4 channel-pairs (lo = even ch, hi = odd ch)
__device__ __forceinline__ void unpack8p(short8 q, f32x2* xa) {
  union { short8 s; unsigned u[4]; } uu; uu.s = q;
#pragma unroll
  for (int j = 0; j < 4; j++) {
    union { unsigned u; float f; } lo, hi;
    lo.u = uu.u[j] << 16;
    hi.u = uu.u[j] & 0xffff0000u;
    xa[j].x = lo.f; xa[j].y = hi.f;
  }
}
// load 8 consecutive f32 as 4 pairs
__device__ __forceinline__ void load8p(const float* p, f32x2* d) {
  float4 a = *(const float4*)p, b = *(const float4*)(p + 4);
  d[0].x = a.x; d[0].y = a.y; d[1].x = a.z; d[1].y = a.w;
  d[2].x = b.x; d[2].y = b.y; d[3].x = b.z; d[3].y = b.w;
}

// DPP-based partial-wave add on the VALU pipe (no LDS).
template <int CTRL>
__device__ __forceinline__ float dppadd(float x) {
  union { float f; int i; } u, v;
  u.f = x;
  v.i = __builtin_amdgcn_update_dpp(0, u.i, CTRL, 0xF, 0xF, true);
  return x + v.f;
}
// sum over each 16-lane group (result in every lane of the group)
__device__ __forceinline__ float red16(float p) {
  p = dppadd<0xB1>(p);    // quad_perm xor1
  p = dppadd<0x4E>(p);    // quad_perm xor2
  p = dppadd<0x124>(p);   // row_ror:4
  p = dppadd<0x128>(p);   // row_ror:8
  return p;
}

// ------------------------- async global->LDS (16B/lane) --------------------
__device__ __forceinline__ void glds16(const bf16* g, bf16* l) {
#if __has_builtin(__builtin_amdgcn_global_load_lds)
  __builtin_amdgcn_global_load_lds(
      (const __attribute__((address_space(1))) void*)g,
      (__attribute__((address_space(3))) void*)l, 16, 0, 0);
#else
  int lane = threadIdx.x & 63;
  ((int4*)l)[lane] = *(const int4*)g;
#endif
}

// ------------------------- bf16 MFMA GEMM ----------------------------------
// C[M,N] = A[M,K] @ BT[N,K]^T. Tile 128x128, BK=32, 4 waves, 64x64 each.
__global__ __launch_bounds__(256)
void gemm_mfma_kernel(const bf16* __restrict__ A, const bf16* __restrict__ BT,
                      bf16* __restrict__ C, int M, int K, int N) {
  __shared__ bf16 lds[8192];           // 16 KiB: A [0,4096), B [4096,8192)
  const int t = threadIdx.x;
  const int w  = t >> 6, l = t & 63;
  const int wr = w >> 1, wc = w & 1;
  const int lo = l & 15, hi = l >> 4;
  const int m0 = blockIdx.y * 128;
  const int n0 = blockIdx.x * 128;

  f32x4 acc[4][4] = {};

  const int c0 = w * 2, c1 = w * 2 + 1;
  const int kc0 = c0 >> 1, r0 = (c0 & 1) * 64 + l;
  const int kc1 = c1 >> 1, r1 = (c1 & 1) * 64 + l;
  int mr0 = m0 + r0; if (mr0 >= M) mr0 = M - 1;
  int mr1 = m0 + r1; if (mr1 >= M) mr1 = M - 1;
  const bf16* ga0 = A + (size_t)mr0 * K + kc0 * 8;
  const bf16* ga1 = A + (size_t)mr1 * K + kc1 * 8;
  const bf16* gb0 = BT + (size_t)(n0 + r0) * K + kc0 * 8;
  const bf16* gb1 = BT + (size_t)(n0 + r1) * K + kc1 * 8;
  bf16* la0 = &lds[c0 * 512];
  bf16* la1 = &lds[c1 * 512];
  bf16* lb0 = &lds[4096 + c0 * 512];
  bf16* lb1 = &lds[4096 + c1 * 512];

  for (int k0 = 0; k0 < K; k0 += 32) {
    if (k0) __syncthreads();
    glds16(ga0 + k0, la0);
    glds16(ga1 + k0, la1);
    glds16(gb0 + k0, lb0);
    glds16(gb1 + k0, lb1);
    __syncthreads();

    short8 af[4], bfr[4];
#pragma unroll
    for (int f = 0; f < 4; f++) {
      af[f]  = *(const short8*)&lds[hi * 1024 + (wr * 64 + f * 16 + lo) * 8];
      bfr[f] = *(const short8*)&lds[4096 + hi * 1024 + (wc * 64 + f * 16 + lo) * 8];
    }
#pragma unroll
    for (int fm = 0; fm < 4; fm++)
#pragma unroll
      for (int fn = 0; fn < 4; fn++)
        acc[fm][fn] = __builtin_amdgcn_mfma_f32_16x16x32_bf16(af[fm], bfr[fn],
                                                              acc[fm][fn], 0, 0, 0);
  }

#pragma unroll
  for (int fm = 0; fm < 4; fm++) {
#pragma unroll
    for (int r = 0; r < 4; r++) {
      int row = m0 + wr * 64 + fm * 16 + hi * 4 + r;
      if (row < M) {
#pragma unroll
        for (int fn = 0; fn < 4; fn++) {
          int col = n0 + wc * 64 + fn * 16 + lo;
          C[(size_t)row * N + col] = __float2bfloat16(acc[fm][fn][r]);
        }
      }
    }
  }
}

// ---- merged prep: blocks [0,512) = weight transposes, [512,...) = x->bf16 -
__global__ __launch_bounds__(256)
void prep_kernel(const float* __restrict__ x, bf16* __restrict__ xb, int n4,
                 const float* __restrict__ Wl1, const float* __restrict__ Wr1,
                 const float* __restrict__ Wl2, const float* __restrict__ Wr2,
                 bf16* __restrict__ W1T, bf16* __restrict__ W2T) {
  const int bid = blockIdx.x;
  if (bid < 512) {
    __shared__ float tile[32][33];
    const int job = bid >> 7, r = bid & 127;
    const float* in; bf16* out; int K, Nn, bx, by;
    if (job == 0)      { in = Wl1; out = W1T;             K = 256; Nn = 512; bx = r & 15; by = r >> 4; }
    else if (job == 1) { in = Wr1; out = W1T + 512 * 256; K = 256; Nn = 512; bx = r & 15; by = r >> 4; }
    else if (job == 2) { in = Wl2; out = W2T;             K = 512; Nn = 256; bx = r & 7;  by = r >> 3; }
    else               { in = Wr2; out = W2T + 256 * 512; K = 512; Nn = 256; bx = r & 7;  by = r >> 3; }
    const int nt = bx * 32, kt = by * 32;
    const int tx = threadIdx.x & 31, ty = threadIdx.x >> 5;
#pragma unroll
    for (int j = 0; j < 4; j++)
      tile[ty + j * 8][tx] = in[(size_t)(kt + ty + j * 8) * Nn + nt + tx];
    __syncthreads();
#pragma unroll
    for (int j = 0; j < 4; j++)
      out[(size_t)(nt + ty + j * 8) * K + kt + tx] = __float2bfloat16(tile[tx][ty + j * 8]);
  } else {
    const int stride = (gridDim.x - 512) * 256;
    for (int i = (bid - 512) * 256 + threadIdx.x; i < n4; i += stride) {
      float4 v = ((const float4*)x)[i];
      union { bf16 h[4]; uint2 u; } cv;
      cv.h[0] = __float2bfloat16(v.x); cv.h[1] = __float2bfloat16(v.y);
      cv.h[2] = __float2bfloat16(v.z); cv.h[3] = __float2bfloat16(v.w);
      ((uint2*)xb)[i] = cv.u;
    }
  }
}

// -------- direct binning fill + edge-attr mean (block-reduced atomics) -----
__global__ __launch_bounds__(256)
void fill_kernel(const int* __restrict__ ei, const float* __restrict__ eattr,
                 int* __restrict__ cnt, int* __restrict__ srcs,
                 float4* __restrict__ eaC, float* __restrict__ sums, int E) {
  __shared__ float4 bred[4];
  int tid = blockIdx.x * blockDim.x + threadIdx.x;
  int stride = gridDim.x * blockDim.x;
  float l0 = 0.f, l1 = 0.f, l2 = 0.f, l3 = 0.f;
  for (int e = tid; e < E; e += stride) {
    int src = ei[e], dst = ei[E + e];
    float4 ea = ((const float4*)eattr)[e];
    int pos = atomicAdd(&cnt[dst], 1);
    if (pos < CAP) {
      int slot = dst * CAP + pos;
      srcs[slot] = src;
      eaC[slot] = ea;
    }
    l0 += ea.x; l1 += ea.y; l2 += ea.z; l3 += ea.w;
  }
#pragma unroll
  for (int o = 1; o < 64; o <<= 1) {
    l0 += __shfl_xor(l0, o); l1 += __shfl_xor(l1, o);
    l2 += __shfl_xor(l2, o); l3 += __shfl_xor(l3, o);
  }
  int wave = threadIdx.x >> 6, lane = threadIdx.x & 63;
  if (lane == 0) bred[wave] = make_float4(l0, l1, l2, l3);
  __syncthreads();
  if (threadIdx.x == 0) {
    float4 a = bred[0], b = bred[1], c = bred[2], d = bred[3];
    atomicAdd(&sums[0], a.x + b.x + c.x + d.x);
    atomicAdd(&sums[1], a.y + b.y + c.y + d.y);
    atomicAdd(&sums[2], a.z + b.z + c.z + d.z);
    atomicAdd(&sums[3], a.w + b.w + c.w + d.w);
  }
}

__global__ void meanw_kernel(const float* __restrict__ sums, float* __restrict__ mean4, float invE) {
  int t = threadIdx.x;
  if (t < 4) mean4[t] = sums[t] * invE;
}

// ---- layer 1 fused: block/node, chunked waves, 4x MLP, packed f32 ---------
// xlr: [N][1024] bf16 = [xl(512) | xr(512)]; lane covers 8 ch, head = lane>>4.
// self-loop (src=v, ea=mean4) computed by wave 0 in-register.
__global__ __launch_bounds__(256, 4)
void fused1_kernel(const int* __restrict__ srcs, const float4* __restrict__ eaC,
                   const int* __restrict__ cnt, const float* __restrict__ mean4,
                   const bf16* __restrict__ xlr,
                   const float* __restrict__ We, const float* __restrict__ att,
                   const float* __restrict__ bias, const float* __restrict__ g,
                   const float* __restrict__ be, bf16* __restrict__ h1) {
  const int v = blockIdx.x;
  const int tid = threadIdx.x;
  const int wave = tid >> 6, lane = tid & 63;
  const int ch = lane * 8;

  f32x2 w0p[4], w1p[4], w2p[4], w3p[4], awp[4], xrp[4];
  load8p(We + 0 * HC1 + ch, w0p);
  load8p(We + 1 * HC1 + ch, w1p);
  load8p(We + 2 * HC1 + ch, w2p);
  load8p(We + 3 * HC1 + ch, w3p);
  load8p(att + ch, awp);
  unpack8p(*(const short8*)(xlr + (size_t)v * 1024 + 512 + ch), xrp);

  int len = cnt[v]; if (len > CAP) len = CAP;
  const int beg = v * CAP, end = beg + len;
  const int chunk = (len + 3) >> 2;       // contiguous quarter per wave
  int ib = beg + wave * chunk;
  int ie = ib + chunk;
  if (ib > end) ib = end;
  if (ie > end) ie = end;

  float den = 0.f;
  f32x2 accp[4] = {};

  auto edge = [&](short8 q, float4 e) {
    f32x2 xa[4]; unpack8p(q, xa);
    f32x2 p2 = {0.f, 0.f};
#pragma unroll
    for (int j = 0; j < 4; j++) {
      f32x2 m = xa[j] + xrp[j];
      m += e.x * w0p[j];
      m += e.y * w1p[j];
      m += e.z * w2p[j];
      m += e.w * w3p[j];
      f32x2 lm = __builtin_elementwise_max(m, m * 0.2f);   // leaky (slope<1)
      p2 += lm * awp[j];
    }
    float p = p2.x + p2.y;
    p = red16(p);                       // per-head sum via DPP (VALU pipe)
    float ex = __expf(p);
    den += ex;
#pragma unroll
    for (int j = 0; j < 4; j++) accp[j] += xa[j] * ex;
  };

  int i = ib;
  for (; i + 4 <= ie; i += 4) {
    int s0 = srcs[i], s1 = srcs[i + 1], s2 = srcs[i + 2], s3 = srcs[i + 3];
    float4 e0 = eaC[i], e1 = eaC[i + 1], e2 = eaC[i + 2], e3 = eaC[i + 3];
    short8 q0 = *(const short8*)(xlr + (size_t)s0 * 1024 + ch);
    short8 q1 = *(const short8*)(xlr + (size_t)s1 * 1024 + ch);
    short8 q2 = *(const short8*)(xlr + (size_t)s2 * 1024 + ch);
    short8 q3 = *(const short8*)(xlr + (size_t)s3 * 1024 + ch);
    edge(q0, e0); edge(q1, e1); edge(q2, e2); edge(q3, e3);
  }
  for (; i < ie; ++i) {
    int s0 = srcs[i];
    float4 e0 = eaC[i];
    short8 q0 = *(const short8*)(xlr + (size_t)s0 * 1024 + ch);
    edge(q0, e0);
  }
  if (wave == 0) {                      // self-loop edge
    float4 e0 = *(const float4*)mean4;
    short8 q0 = *(const short8*)(xlr + (size_t)v * 1024 + ch);
    edge(q0, e0);
  }

  // ----- cross-wave combine -----
  __shared__ float accs[4][HC1];
  __shared__ float dens[4][4];     // [wave][head]
  __shared__ float2 red[4];
  *(float4*)&accs[wave][ch]     = *(float4*)&accp[0];
  *(float4*)&accs[wave][ch + 4] = *(float4*)&accp[2];
  if ((lane & 15) == 0) dens[wave][lane >> 4] = den;   // per-head partial
  __syncthreads();

  const int c = tid * 2;          // each thread: 2 channels for epilogue
  const int head = c >> 7;        // 128 channels per head
  const float dtot = dens[0][head] + dens[1][head] + dens[2][head] + dens[3][head];
  const float rden = 1.f / (dtot + 1e-16f);
  float2 a0 = *(float2*)&accs[0][c];
  float2 a1 = *(float2*)&accs[1][c];
  float2 a2 = *(float2*)&accs[2][c];
  float2 a3 = *(float2*)&accs[3][c];
  float2 bv = *(const float2*)(bias + c);
  float val0 = (a0.x + a1.x + a2.x + a3.x) * rden + bv.x;
  float val1 = (a0.y + a1.y + a2.y + a3.y) * rden + bv.y;

  float s1 = val0 + val1, s2 = val0 * val0 + val1 * val1;
  s1 = red16(s1); s2 = red16(s2);
  s1 += __shfl_xor(s1, 16); s2 += __shfl_xor(s2, 16);
  s1 += __shfl_xor(s1, 32); s2 += __shfl_xor(s2, 32);
  if (lane == 0) red[wave] = make_float2(s1, s2);
  __syncthreads();
  float ts1 = red[0].x + red[1].x + red[2].x + red[3].x;
  float ts2 = red[0].y + red[1].y + red[2].y + red[3].y;
  float mu  = ts1 * (1.f / HC1);
  float var = ts2 * (1.f / HC1) - mu * mu;
  float rs  = rsqrtf(var + 1e-5f);

  float2 gv = *(const float2*)(g + c);
  float2 ev = *(const float2*)(be + c);
  float ya = (val0 - mu) * rs * gv.x + ev.x;
  float yb = (val1 - mu) * rs * gv.y + ev.y;
  ya = (ya > 0.f) ? ya : expm1f(ya);
  yb = (yb > 0.f) ? yb : expm1f(yb);
  bf162 hv;
  hv.x = __float2bfloat16(ya); hv.y = __float2bfloat16(yb);
  *(bf162*)(h1 + (size_t)v * HC1 + c) = hv;
}

// ---- layer 2 fused: half-wave 2-edge layout, 16B/lane gathers -------------
// xlr: [N][512] bf16 = [xl(256) | xr(256)].
// lanes 0-31 = edge A, lanes 32-63 = edge B; each lane covers 8 ch (hl*8).
__global__ __launch_bounds__(256, 3)
void fused2_kernel(const int* __restrict__ srcs, const float4* __restrict__ eaC,
                   const int* __restrict__ cnt, const float* __restrict__ mean4,
                   const bf16* __restrict__ xlr,
                   const float* __restrict__ We, const float* __restrict__ att,
                   const float* __restrict__ bias, const float* __restrict__ g,
                   const float* __restrict__ be, const float* __restrict__ xin,
                   float* __restrict__ out) {
  const int v = blockIdx.x;
  const int tid = threadIdx.x;
  const int wave = tid >> 6, lane = tid & 63;
  const int half = lane >> 5;          // 0: edge A, 1: edge B
  const int hl = lane & 31;
  const int c0 = hl * 8;               // 8 channels per lane

  f32x2 w0p[4], w1p[4], w2p[4], w3p[4], atp[4], xrp[4];
  load8p(We + 0 * HC2 + c0, w0p);
  load8p(We + 1 * HC2 + c0, w1p);
  load8p(We + 2 * HC2 + c0, w2p);
  load8p(We + 3 * HC2 + c0, w3p);
  load8p(att + c0, atp);
  unpack8p(*(const short8*)(xlr + (size_t)v * 512 + 256 + c0), xrp);

  int len = cnt[v]; if (len > CAP) len = CAP;
  const int beg = v * CAP, end = beg + len;
  const int chunk = (len + 3) >> 2;
  int ib = beg + wave * chunk;
  int ie = ib + chunk;
  if (ib > end) ib = end;
  if (ie > end) ie = end;

  float den = 0.f;                 // per-half partial (A-half / B-half)
  f32x2 accp[4] = {};

  // one PAIR of edges (A in lanes<32, B in lanes>=32). bvalid: B edge exists.
  auto pair = [&](short8 q, float4 e, bool bvalid) {
    f32x2 xa[4]; unpack8p(q, xa);
    f32x2 p2 = {0.f, 0.f};
#pragma unroll
    for (int j = 0; j < 4; j++) {
      f32x2 m = xa[j] + xrp[j];
      m += e.x * w0p[j];
      m += e.y * w1p[j];
      m += e.z * w2p[j];
      m += e.w * w3p[j];
      f32x2 lm = __builtin_elementwise_max(m, m * 0.2f);
      p2 += lm * atp[j];
    }
    float p = p2.x + p2.y;
    p = red16(p);
    p += __shfl_xor(p, 16);          // sum over 32-lane half
    float ex = __expf(p);
    if (half && !bvalid) ex = 0.f;   // mask missing B edge
    den += ex;
#pragma unroll
    for (int j = 0; j < 4; j++) accp[j] += xa[j] * ex;
  };

  int i = ib;
  for (; i + 4 <= ie; i += 4) {
    int sA = srcs[i + half],   sB = srcs[i + 2 + half];
    float4 eA = eaC[i + half], eB = eaC[i + 2 + half];
    short8 qA = *(const short8*)(xlr + (size_t)sA * 512 + c0);
    short8 qB = *(const short8*)(xlr + (size_t)sB * 512 + c0);
    pair(qA, eA, true); pair(qB, eB, true);
  }
  for (; i < ie; i += 2) {
    bool hasB = (i + 1 < ie);
    int idx = i + half; if (idx > ie - 1) idx = i;   // clamp invalid B
    int s = srcs[idx];
    float4 e = eaC[idx];
    short8 q = *(const short8*)(xlr + (size_t)s * 512 + c0);
    pair(q, e, hasB);
  }
  if (wave == 0) {                   // self-loop edge (A half only)
    float4 e = *(const float4*)mean4;
    short8 q = *(const short8*)(xlr + (size_t)v * 512 + c0);
    pair(q, e, false);
  }

  // combine the two halves (each lane hl holds same channels in both halves)
#pragma unroll
  for (int j = 0; j < 4; j++) {
    accp[j].x += __shfl_xor(accp[j].x, 32);
    accp[j].y += __shfl_xor(accp[j].y, 32);
  }
  den += __shfl_xor(den, 32);

  // ----- cross-wave combine -----
  __shared__ float accs[4][HC2];
  __shared__ float dens[4];
  __shared__ float2 red[4];
  if (half == 0) {
    *(float4*)&accs[wave][c0]     = *(float4*)&accp[0];
    *(float4*)&accs[wave][c0 + 4] = *(float4*)&accp[2];
  }
  if (lane == 0) dens[wave] = den;
  __syncthreads();

  const int c = tid;              // each thread: 1 channel
  const float dtot = dens[0] + dens[1] + dens[2] + dens[3];
  const float rden = 1.f / (dtot + 1e-16f);
  float val = (accs[0][c] + accs[1][c] + accs[2][c] + accs[3][c]) * rden + bias[c];

  float s1 = val, s2 = val * val;
  s1 = red16(s1); s2 = red16(s2);
  s1 += __shfl_xor(s1, 16); s2 += __shfl_xor(s2, 16);
  s1 += __shfl_xor(s1, 32); s2 += __shfl_xor(s2, 32);
  if (lane == 0) red[wave] = make_float2(s1, s2);
  __syncthreads();
  float ts1 = red[0].x + red[1].x + red[2].x + red[3].x;
  float ts2 = red[0].y + red[1].y + red[2].y + red[3].y;
  float mu  = ts1 * (1.f / HC2);
  float var = ts2 * (1.f / HC2) - mu * mu;
  float rs  = rsqrtf(var + 1e-5f);
  float y = (val - mu) * rs * g[c] + be[c];
  out[(size_t)v * HC2 + c] = y + xin[(size_t)v * HC2 + c];
}

// ---------------------------------------------------------------------------
extern "C" void kernel_launch(void* const* d_in, const int* in_sizes, int n_in,
                              void* d_out, int out_size, void* d_ws, size_t ws_size,
                              hipStream_t stream) {
  const float* x     = (const float*)d_in[0];
  const int*   ei    = (const int*)d_in[1];
  const float* eattr = (const float*)d_in[2];
  const float* Wl1   = (const float*)d_in[3];
  const float* Wr1   = (const float*)d_in[4];
  const float* We1   = (const float*)d_in[5];
  const float* att1  = (const float*)d_in[6];
  const float* b1    = (const float*)d_in[7];
  const float* g1    = (const float*)d_in[8];
  const float* be1   = (const float*)d_in[9];
  const float* Wl2   = (const float*)d_in[10];
  const float* Wr2   = (const float*)d_in[11];
  const float* We2   = (const float*)d_in[12];
  const float* att2  = (const float*)d_in[13];
  const float* b2    = (const float*)d_in[14];
  const float* g2    = (const float*)d_in[15];
  const float* be2   = (const float*)d_in[16];

  const int N    = in_sizes[0] / D_IN;   // 10000
  const int E    = in_sizes[2] / 4;      // 320000

  char* w = (char*)d_ws;
  auto alloc = [&](size_t bytes) -> void* {
    void* p = (void*)w;
    w += (bytes + 255) & ~(size_t)255;
    return p;
  };
  bf16*   xb    = (bf16*)alloc((size_t)N * D_IN * 2);
  bf16*   W1T   = (bf16*)alloc((size_t)1024 * 256 * 2);
  bf16*   W2T   = (bf16*)alloc((size_t)512 * 512 * 2);
  bf16*   xlr1  = (bf16*)alloc((size_t)N * 1024 * 2);
  bf16*   h1    = (bf16*)alloc((size_t)N * HC1 * 2);
  bf16*   xlr2  = (bf16*)alloc((size_t)N * 512 * 2);
  int*    srcs  = (int*)alloc((size_t)N * CAP * 4);
  float4* eaC   = (float4*)alloc((size_t)N * CAP * 16);
  float*  mean4 = (float*)alloc(64);
  char*   zb    = w;                     // zeroed region
  int*    cnt   = (int*)alloc((size_t)N * 4);
  float*  sums  = (float*)alloc(64);
  size_t  zbytes = (size_t)(w - zb);

  hipMemsetAsync(zb, 0, zbytes, stream);

  int n4 = N * D_IN / 4;
  prep_kernel<<<512 + 640, 256, 0, stream>>>(x, xb, n4, Wl1, Wr1, Wl2, Wr2, W1T, W2T);

  fill_kernel<<<1024, 256, 0, stream>>>(ei, eattr, cnt, srcs, eaC, sums, E);
  meanw_kernel<<<1, 64, 0, stream>>>(sums, mean4, 1.f / (float)E);

  dim3 gg1(1024 / 128, (N + 127) / 128);
  gemm_mfma_kernel<<<gg1, 256, 0, stream>>>(xb, W1T, xlr1, N, 256, 1024);

  fused1_kernel<<<N, 256, 0, stream>>>(srcs, eaC, cnt, mean4, xlr1, We1, att1,
                                       b1, g1, be1, h1);

  dim3 gg2(512 / 128, (N + 127) / 128);
  gemm_mfma_kernel<<<gg2, 256, 0, stream>>>(h1, W2T, xlr2, N, 512, 512);

  fused2_kernel<<<N, 256, 0, stream>>>(srcs, eaC, cnt, mean4, xlr2, We2, att2,
                                       b2, g2, be2, x, (float*)d_out);
}